// Round 8
// baseline (486.014 us; speedup 1.0000x reference)
//
#include <hip/hip_runtime.h>
#include <stdint.h>

// Triaffine: out[b,z,x,y] = sum_{i,j,k} xb[x,i] z[z,k] W[i,k,j] yb[y,j]
// B=4, S=128, D=512.  W: [513][512][513] f32 (i,k,j), elem (i,k,j) at (i*512+k)*513+j.
//
// Decomposition (bias split so all GEMM dims are 512):
//   M[bz,i,j] = sum_k z[bz,k] W[i,k,j]      (i,j < 512)  -- k_gemm1 (bf16 out, 268 MB)
//   R[bz,y,i] = sum_j M[bz,i,j] Y[b,y,j]                 -- k_p2   (bf16 out, 67 MB)
//   out[bz,x,y] = sum_i X[b,x,i] R[bz,y,i] + u+v+d       -- k_p3
//   a[bz,i], c[bz,j], d[bz] from W edges (k_edge); u=x.a, v=y.c (k_uv)

typedef __attribute__((ext_vector_type(8))) short bf16x8;
typedef __attribute__((ext_vector_type(4))) float f32x4;

__device__ __forceinline__ unsigned short f2bf(float f) {
    unsigned int u = __float_as_uint(f);
    u += 0x7fffu + ((u >> 16) & 1u);      // RNE
    return (unsigned short)(u >> 16);
}

__device__ __forceinline__ void gload_lds16(const void* g, void* l) {
    __builtin_amdgcn_global_load_lds((const __attribute__((address_space(1))) void*)g,
                                     (__attribute__((address_space(3))) void*)l, 16, 0, 0);
}

// ---------------- cast x,y,z -> bf16 ----------------
__global__ __launch_bounds__(256) void k_cast(const float* __restrict__ x,
    const float* __restrict__ y, const float* __restrict__ z,
    unsigned short* __restrict__ xbf, unsigned short* __restrict__ ybf,
    unsigned short* __restrict__ zbf)
{
    int t = blockIdx.x * 256 + threadIdx.x;   // 98304 threads, 8 elems each
    int arr = t >> 15;
    int off = (t & 32767) * 8;
    const float* src = (arr == 0) ? x : (arr == 1) ? y : z;
    unsigned short* dst = (arr == 0) ? xbf : (arr == 1) ? ybf : zbf;
    float4 a = *(const float4*)(src + off);
    float4 b = *(const float4*)(src + off + 4);
    uint4 o;
    o.x = f2bf(a.x) | ((unsigned)f2bf(a.y) << 16);
    o.y = f2bf(a.z) | ((unsigned)f2bf(a.w) << 16);
    o.z = f2bf(b.x) | ((unsigned)f2bf(b.y) << 16);
    o.w = f2bf(b.z) | ((unsigned)f2bf(b.w) << 16);
    *(uint4*)(dst + off) = o;
}

// ---------------- bias-edge GEMMs ----------------
__global__ __launch_bounds__(256) void k_edge(const float* __restrict__ z,
    const float* __restrict__ w, float* __restrict__ a_arr,
    float* __restrict__ c_arr, float* __restrict__ d_arr)
{
    __shared__ float Zs[64][33];
    __shared__ float Bs[32][65];
    int t = threadIdx.x;
    int mb = blockIdx.x % 17, bzb = blockIdx.x / 17;
    int tr = t >> 4, tc = t & 15;
    float acc[4][4] = {};
    for (int k0 = 0; k0 < 512; k0 += 32) {
        __syncthreads();
        {   int row = t >> 2, ko = (t & 3) * 8;
            const float* p = z + (bzb * 64 + row) * 512 + k0 + ko;
            float4 v0 = ((const float4*)p)[0], v1 = ((const float4*)p)[1];
            Zs[row][ko + 0] = v0.x; Zs[row][ko + 1] = v0.y; Zs[row][ko + 2] = v0.z; Zs[row][ko + 3] = v0.w;
            Zs[row][ko + 4] = v1.x; Zs[row][ko + 5] = v1.y; Zs[row][ko + 6] = v1.z; Zs[row][ko + 7] = v1.w;
        }
        {   int kr = t >> 3, mo = (t & 7) * 8;
            for (int e = 0; e < 8; ++e) {
                int m = mb * 64 + mo + e;
                float v = 0.f;
                int krow = k0 + kr;
                if (m < 512)        v = w[(m * 512 + krow) * 513 + 512];
                else if (m < 1024)  v = w[(262144 + krow) * 513 + (m - 512)];
                else if (m == 1024) v = w[(262144 + krow) * 513 + 512];
                Bs[kr][mo + e] = v;
            }
        }
        __syncthreads();
        for (int kk = 0; kk < 32; ++kk) {
            float zr[4], br[4];
            for (int r = 0; r < 4; ++r) zr[r] = Zs[tr * 4 + r][kk];
            for (int c = 0; c < 4; ++c) br[c] = Bs[kk][tc * 4 + c];
            for (int r = 0; r < 4; ++r)
                for (int c = 0; c < 4; ++c) acc[r][c] += zr[r] * br[c];
        }
    }
    for (int r = 0; r < 4; ++r)
        for (int c = 0; c < 4; ++c) {
            int bz = bzb * 64 + tr * 4 + r;
            int m = mb * 64 + tc * 4 + c;
            if (m < 512)        a_arr[bz * 512 + m] = acc[r][c];
            else if (m < 1024)  c_arr[bz * 512 + (m - 512)] = acc[r][c];
            else if (m == 1024) d_arr[bz] = acc[r][c];
        }
}

// ---------------- k_uv: u[bz,x] = x.a_bz, v[bz,y] = y.c_bz (coalesced) ----------------
__global__ __launch_bounds__(512) void k_uv(const float* __restrict__ xf,
    const float* __restrict__ yf, const float* __restrict__ a_arr,
    const float* __restrict__ c_arr, float* __restrict__ u_arr,
    float* __restrict__ v_arr)
{
    __shared__ float part[512];
    int bz = blockIdx.x;
    int b = bz >> 7;
    int t = threadIdx.x, r = t >> 2, q = t & 3;
    {
        const float* xp = xf + (size_t)(b * 128 + r) * 512;
        const float* ap = a_arr + bz * 512;
        float s = 0.f;
        #pragma unroll 4
        for (int c0 = 0; c0 < 32; ++c0) {
            int col = c0 * 16 + q * 4;
            float4 xv = *(const float4*)(xp + col);
            float4 av = *(const float4*)(ap + col);
            s += xv.x * av.x + xv.y * av.y + xv.z * av.z + xv.w * av.w;
        }
        part[t] = s;
    }
    __syncthreads();
    if (t < 128) u_arr[bz * 128 + t] = part[t*4] + part[t*4+1] + part[t*4+2] + part[t*4+3];
    __syncthreads();
    {
        const float* yp = yf + (size_t)(b * 128 + r) * 512;
        const float* cp = c_arr + bz * 512;
        float s = 0.f;
        #pragma unroll 4
        for (int c0 = 0; c0 < 32; ++c0) {
            int col = c0 * 16 + q * 4;
            float4 yv = *(const float4*)(yp + col);
            float4 cv = *(const float4*)(cp + col);
            s += yv.x * cv.x + yv.y * cv.y + yv.z * cv.z + yv.w * cv.w;
        }
        part[t] = s;
    }
    __syncthreads();
    if (t < 128) v_arr[bz * 128 + t] = part[t*4] + part[t*4+1] + part[t*4+2] + part[t*4+3];
}

// ---------------- G1 (unchanged from round 7) ----------------
__global__ __launch_bounds__(512, 2) void k_gemm1(const unsigned short* __restrict__ zbf,
    const float* __restrict__ w, unsigned short* __restrict__ Mws)
{
    extern __shared__ unsigned char smem[];
    unsigned char* Zb0 = smem;                 // [512 rows][32 k] bf16 = 32 KB
    unsigned char* Zb1 = smem + 32768;
    unsigned char* Bb0 = smem + 65536;         // [128 j][32 k] bf16 = 8 KB
    unsigned char* Bb1 = smem + 73728;         // total 81920 B

    int nwg = gridDim.x, cpx = nwg >> 3;
    int bid = blockIdx.x;
    int swz = (bid & 7) * cpx + (bid >> 3);    // XCD swizzle (nwg % 8 == 0)
    int iloc = swz >> 2, jb = swz & 3;
    int j0 = jb * 128;
    int t = threadIdx.x, wid = t >> 6, lane = t & 63;
    int bzg = wid >> 1, jg = wid & 1;
    int l15 = lane & 15, l4 = lane >> 4;

    int arow = lane >> 2;
    int akc  = (lane & 3) ^ ((lane >> 3) & 3);
    const unsigned short* zbase = zbf + (size_t)(wid * 64 + arow) * 512 + akc * 8;

    int jB = t & 127, kq8 = t >> 7;
    const float* wb = w + (size_t)iloc * 262656 + (size_t)(kq8 * 8) * 513 + j0 + jB;
    int bwoff = jB * 64 + ((kq8 ^ ((jB >> 1) & 3)) * 16);

    int aoff = (bzg * 128 + l15) * 64 + ((l4 ^ ((l15 >> 1) & 3)) * 16);
    int boff = (jg * 64 + l15) * 64 + ((l4 ^ ((l15 >> 1) & 3)) * 16);

    f32x4 acc[8][4];
    #pragma unroll
    for (int mt = 0; mt < 8; ++mt)
        #pragma unroll
        for (int nt = 0; nt < 4; ++nt) acc[mt][nt] = (f32x4){0.f, 0.f, 0.f, 0.f};

    float wr[2][8];

    #pragma unroll
    for (int q = 0; q < 4; ++q)
        gload_lds16(zbase + q * 8192, Zb0 + wid * 4096 + q * 1024);
    {
        #pragma unroll
        for (int e = 0; e < 8; ++e) wr[0][e] = __builtin_nontemporal_load(wb + (size_t)e * 513);
        const float* wp = wb + (size_t)32 * 513;
        #pragma unroll
        for (int e = 0; e < 8; ++e) wr[1][e] = __builtin_nontemporal_load(wp + (size_t)e * 513);
        uint4 pk;
        pk.x = f2bf(wr[0][0]) | ((unsigned)f2bf(wr[0][1]) << 16);
        pk.y = f2bf(wr[0][2]) | ((unsigned)f2bf(wr[0][3]) << 16);
        pk.z = f2bf(wr[0][4]) | ((unsigned)f2bf(wr[0][5]) << 16);
        pk.w = f2bf(wr[0][6]) | ((unsigned)f2bf(wr[0][7]) << 16);
        *(uint4*)(Bb0 + bwoff) = pk;
    }
    asm volatile("s_waitcnt lgkmcnt(0)" ::: "memory");
    __builtin_amdgcn_s_barrier();
    __builtin_amdgcn_sched_barrier(0);

    #pragma unroll
    for (int ks = 0; ks < 16; ++ks) {
        const int cur = ks & 1;
        unsigned char* Zcur  = cur ? Zb1 : Zb0;
        unsigned char* Znext = cur ? Zb0 : Zb1;
        unsigned char* Bcur  = cur ? Bb1 : Bb0;
        unsigned char* Bnext = cur ? Bb0 : Bb1;

        if (ks < 15) {
            #pragma unroll
            for (int q = 0; q < 4; ++q)
                gload_lds16(zbase + (ks + 1) * 32 + q * 8192, Znext + wid * 4096 + q * 1024);
        }
        if (ks < 14) {
            const float* wp = wb + (size_t)(ks + 2) * 32 * 513;
            #pragma unroll
            for (int e = 0; e < 8; ++e) wr[cur][e] = __builtin_nontemporal_load(wp + (size_t)e * 513);
        }
        bf16x8 bfr[4];
        #pragma unroll
        for (int nt = 0; nt < 4; ++nt)
            bfr[nt] = *(const bf16x8*)(Bcur + boff + nt * 1024);
        #pragma unroll
        for (int mt = 0; mt < 8; ++mt) {
            bf16x8 afr = *(const bf16x8*)(Zcur + aoff + mt * 1024);
            #pragma unroll
            for (int nt = 0; nt < 4; ++nt)
                acc[mt][nt] = __builtin_amdgcn_mfma_f32_16x16x32_bf16(afr, bfr[nt], acc[mt][nt], 0, 0, 0);
        }
        if (ks < 15) {
            uint4 pk;
            pk.x = f2bf(wr[cur ^ 1][0]) | ((unsigned)f2bf(wr[cur ^ 1][1]) << 16);
            pk.y = f2bf(wr[cur ^ 1][2]) | ((unsigned)f2bf(wr[cur ^ 1][3]) << 16);
            pk.z = f2bf(wr[cur ^ 1][4]) | ((unsigned)f2bf(wr[cur ^ 1][5]) << 16);
            pk.w = f2bf(wr[cur ^ 1][6]) | ((unsigned)f2bf(wr[cur ^ 1][7]) << 16);
            *(uint4*)(Bnext + bwoff) = pk;
        }
        if (ks < 14) {
            asm volatile("s_waitcnt vmcnt(8) lgkmcnt(0)" ::: "memory");
        } else if (ks == 14) {
            asm volatile("s_waitcnt vmcnt(0) lgkmcnt(0)" ::: "memory");
        }
        if (ks < 15) {
            __builtin_amdgcn_s_barrier();
            __builtin_amdgcn_sched_barrier(0);
        }
    }

    #pragma unroll
    for (int mt = 0; mt < 8; ++mt)
        #pragma unroll
        for (int nt = 0; nt < 4; ++nt)
            #pragma unroll
            for (int r = 0; r < 4; ++r) {
                int bz = bzg * 128 + mt * 16 + l4 * 4 + r;
                int j  = j0 + jg * 64 + nt * 16 + l15;
                Mws[(size_t)bz * 262144 + (size_t)iloc * 512 + j] = f2bf(acc[mt][nt][r]);
            }
}

// ---------------- k_p2: R[bz,y,i] = sum_j M[bz,i,j] Y[b,y,j] ----------------
// 2048 WGs = 512 bz x 4 i-blocks; 512 thr, 8 waves = 4 ig x 2 yg; wave 32i x 64y.
// 32 KB LDS (M/Y tiles, BK=32, dbuf) -> multi-WG/CU; gload_lds staging, swizzled.
__global__ __launch_bounds__(512, 4) void k_p2(const unsigned short* __restrict__ Mws,
    const unsigned short* __restrict__ ybf, unsigned short* __restrict__ Rws)
{
    __shared__ unsigned char Mt[2][8192];      // [128 i][32 j] bf16, slot^=(row&3)
    __shared__ unsigned char Yt[2][8192];      // [128 y][32 j] bf16
    int bid = blockIdx.x;
    int swz = (bid & 7) * 256 + (bid >> 3);    // XCD swizzle (2048 % 8 == 0)
    int bz = swz >> 2, ib = swz & 3;
    int b = bz >> 7;
    int t = threadIdx.x, wid = t >> 6, lane = t & 63;
    int l15 = lane & 15, l4 = lane >> 4;
    int ig = wid >> 1, yg = wid & 1;

    int srow = t >> 2;                         // 0..127
    int sch  = (t & 3) ^ (srow & 3);           // pre-swizzled 16B chunk
    const unsigned short* msrc = Mws + (size_t)bz * 262144 + (size_t)(ib * 128 + srow) * 512 + sch * 8;
    const unsigned short* ysrc = ybf + (size_t)(b * 128 + srow) * 512 + sch * 8;

    f32x4 acc[2][4];
    #pragma unroll
    for (int mt = 0; mt < 2; ++mt)
        #pragma unroll
        for (int nt = 0; nt < 4; ++nt) acc[mt][nt] = (f32x4){0.f, 0.f, 0.f, 0.f};

    gload_lds16(msrc, &Mt[0][t * 16]);
    gload_lds16(ysrc, &Yt[0][t * 16]);
    asm volatile("s_waitcnt vmcnt(0)" ::: "memory");
    __builtin_amdgcn_s_barrier();
    __builtin_amdgcn_sched_barrier(0);

    #pragma unroll
    for (int ks = 0; ks < 16; ++ks) {
        const int cur = ks & 1;
        if (ks < 15) {
            gload_lds16(msrc + (ks + 1) * 32, &Mt[cur ^ 1][t * 16]);
            gload_lds16(ysrc + (ks + 1) * 32, &Yt[cur ^ 1][t * 16]);
        }
        bf16x8 afr[2], bfr[4];
        #pragma unroll
        for (int mt = 0; mt < 2; ++mt) {
            int r2 = ig * 32 + mt * 16 + l15;
            afr[mt] = *(const bf16x8*)(&Mt[cur][r2 * 64 + ((l4 ^ (r2 & 3)) * 16)]);
        }
        #pragma unroll
        for (int nt = 0; nt < 4; ++nt) {
            int r2 = yg * 64 + nt * 16 + l15;
            bfr[nt] = *(const bf16x8*)(&Yt[cur][r2 * 64 + ((l4 ^ (r2 & 3)) * 16)]);
        }
        #pragma unroll
        for (int mt = 0; mt < 2; ++mt)
            #pragma unroll
            for (int nt = 0; nt < 4; ++nt)
                acc[mt][nt] = __builtin_amdgcn_mfma_f32_16x16x32_bf16(afr[mt], bfr[nt], acc[mt][nt], 0, 0, 0);
        if (ks < 15) {
            asm volatile("s_waitcnt vmcnt(0)" ::: "memory");
            __builtin_amdgcn_s_barrier();
            __builtin_amdgcn_sched_barrier(0);
        }
    }

    // R[bz][y][ib*128 + i] bf16; per (mt,nt): lane packs 4 consecutive i
    #pragma unroll
    for (int mt = 0; mt < 2; ++mt)
        #pragma unroll
        for (int nt = 0; nt < 4; ++nt) {
            int y = yg * 64 + nt * 16 + l15;
            int i = ib * 128 + ig * 32 + mt * 16 + l4 * 4;
            unsigned p0 = f2bf(acc[mt][nt][0]) | ((unsigned)f2bf(acc[mt][nt][1]) << 16);
            unsigned p1 = f2bf(acc[mt][nt][2]) | ((unsigned)f2bf(acc[mt][nt][3]) << 16);
            *(uint2*)(Rws + (size_t)bz * 65536 + (size_t)y * 512 + i) = make_uint2(p0, p1);
        }
}

// ---------------- k_p3: out[bz,x,y] = sum_i X[b,x,i] R[bz,y,i] + u+v+d ----------------
// 512 WGs (one bz); 512 thr, 8 waves = 2 xg x 4 yg; wave 64x x 32y; K=512 i, BK=32.
__global__ __launch_bounds__(512, 4) void k_p3(const unsigned short* __restrict__ xbf,
    const unsigned short* __restrict__ Rws, const float* __restrict__ u_arr,
    const float* __restrict__ v_arr, const float* __restrict__ d_arr,
    float* __restrict__ out)
{
    __shared__ unsigned char Xt[2][8192];      // [128 x][32 i] bf16, slot^=(row&3)
    __shared__ unsigned char Rt[2][8192];      // [128 y][32 i] bf16
    int bid = blockIdx.x;
    int bz = (bid & 7) * 64 + (bid >> 3);      // XCD swizzle (512 = 8*64)
    int b = bz >> 7;
    int t = threadIdx.x, wid = t >> 6, lane = t & 63;
    int l15 = lane & 15, l4 = lane >> 4;
    int xg = wid >> 2, yg = wid & 3;

    int srow = t >> 2;
    int sch  = (t & 3) ^ (srow & 3);
    const unsigned short* xsrc = xbf + (size_t)(b * 128 + srow) * 512 + sch * 8;
    const unsigned short* rsrc = Rws + (size_t)bz * 65536 + (size_t)srow * 512 + sch * 8;

    f32x4 acc[4][2];
    #pragma unroll
    for (int mt = 0; mt < 4; ++mt)
        #pragma unroll
        for (int nt = 0; nt < 2; ++nt) acc[mt][nt] = (f32x4){0.f, 0.f, 0.f, 0.f};

    gload_lds16(xsrc, &Xt[0][t * 16]);
    gload_lds16(rsrc, &Rt[0][t * 16]);
    asm volatile("s_waitcnt vmcnt(0)" ::: "memory");
    __builtin_amdgcn_s_barrier();
    __builtin_amdgcn_sched_barrier(0);

    #pragma unroll
    for (int ks = 0; ks < 16; ++ks) {
        const int cur = ks & 1;
        if (ks < 15) {
            gload_lds16(xsrc + (ks + 1) * 32, &Xt[cur ^ 1][t * 16]);
            gload_lds16(rsrc + (ks + 1) * 32, &Rt[cur ^ 1][t * 16]);
        }
        bf16x8 afr[4], bfr[2];
        #pragma unroll
        for (int mt = 0; mt < 4; ++mt) {
            int r2 = xg * 64 + mt * 16 + l15;
            afr[mt] = *(const bf16x8*)(&Xt[cur][r2 * 64 + ((l4 ^ (r2 & 3)) * 16)]);
        }
        #pragma unroll
        for (int nt = 0; nt < 2; ++nt) {
            int r2 = yg * 32 + nt * 16 + l15;
            bfr[nt] = *(const bf16x8*)(&Rt[cur][r2 * 64 + ((l4 ^ (r2 & 3)) * 16)]);
        }
        #pragma unroll
        for (int mt = 0; mt < 4; ++mt)
            #pragma unroll
            for (int nt = 0; nt < 2; ++nt)
                acc[mt][nt] = __builtin_amdgcn_mfma_f32_16x16x32_bf16(afr[mt], bfr[nt], acc[mt][nt], 0, 0, 0);
        if (ks < 15) {
            asm volatile("s_waitcnt vmcnt(0)" ::: "memory");
            __builtin_amdgcn_s_barrier();
            __builtin_amdgcn_sched_barrier(0);
        }
    }

    // epilogue: out = acc + u[x] + v[y] + d
    float dv = d_arr[bz];
    float* op = out + (size_t)bz * 16384;
    #pragma unroll
    for (int mt = 0; mt < 4; ++mt) {
        float4 uq = *(const float4*)(u_arr + bz * 128 + xg * 64 + mt * 16 + l4 * 4);
        #pragma unroll
        for (int nt = 0; nt < 2; ++nt) {
            int y = yg * 32 + nt * 16 + l15;
            float vv = v_arr[bz * 128 + y] + dv;
            int x0 = xg * 64 + mt * 16 + l4 * 4;
            op[(x0 + 0) * 128 + y] = acc[mt][nt][0] + uq.x + vv;
            op[(x0 + 1) * 128 + y] = acc[mt][nt][1] + uq.y + vv;
            op[(x0 + 2) * 128 + y] = acc[mt][nt][2] + uq.z + vv;
            op[(x0 + 3) * 128 + y] = acc[mt][nt][3] + uq.w + vv;
        }
    }
}

extern "C" void kernel_launch(void* const* d_in, const int* in_sizes, int n_in,
                              void* d_out, int out_size, void* d_ws, size_t ws_size,
                              hipStream_t stream)
{
    const float* x = (const float*)d_in[0];
    const float* y = (const float*)d_in[1];
    const float* z = (const float*)d_in[2];
    const float* w = (const float*)d_in[3];
    float* out = (float*)d_out;
    char* ws = (char*)d_ws;

    unsigned short* xbf  = (unsigned short*)(ws + 0);          // 512 KB
    unsigned short* ybf  = (unsigned short*)(ws + 524288);     // 512 KB
    unsigned short* zbf  = (unsigned short*)(ws + 1048576);    // 512 KB
    float* a_arr = (float*)(ws + 1572864);                     // 1 MB
    float* c_arr = (float*)(ws + 2621440);                     // 1 MB
    float* d_arr = (float*)(ws + 3670016);                     // 2 KB
    float* u_arr = (float*)(ws + 3674112);                     // 256 KB
    float* v_arr = (float*)(ws + 3936256);                     // 256 KB
    unsigned short* Mws = (unsigned short*)(ws + 4198400);     // 268 MB
    unsigned short* Rws = (unsigned short*)(ws + 272633856);   // 67 MB

    hipLaunchKernelGGL(k_cast, dim3(384), dim3(256), 0, stream, x, y, z, xbf, ybf, zbf);
    hipLaunchKernelGGL(k_edge, dim3(136), dim3(256), 0, stream, z, w, a_arr, c_arr, d_arr);
    hipLaunchKernelGGL(k_uv, dim3(512), dim3(512), 0, stream, x, y, a_arr, c_arr, u_arr, v_arr);
    hipLaunchKernelGGL(k_gemm1, dim3(2048), dim3(512), 81920, stream, zbf, w, Mws);
    hipLaunchKernelGGL(k_p2, dim3(2048), dim3(512), 0, stream, Mws, ybf, Rws);
    hipLaunchKernelGGL(k_p3, dim3(512), dim3(512), 0, stream, xbf, Rws, u_arr, v_arr, d_arr, out);
}